// Round 1
// baseline (1452.641 us; speedup 1.0000x reference)
//
#include <hip/hip_runtime.h>
#include <math.h>

#define N_NODES 50000
#define F_IN 128
#define HID 128
#define N_CLS 2
#define E_RAW 800000
#define E_TOT (E_RAW + N_NODES)   // self-loops appended
#define NEG_SLOPE 0.2f

// ---------------------------------------------------------------------------
// Kernel 1: fused GEMM  X[N,128] @ [Wl1 | Wr1 | Wlin1] -> XL, XR, LIN (each [N,128])
// Each thread: 64-lane col within a 64-col tile, 8 rows register-blocked.
// ---------------------------------------------------------------------------
__global__ __launch_bounds__(256) void gemm1_kernel(
    const float* __restrict__ x,
    const float* __restrict__ Wl, const float* __restrict__ Wr,
    const float* __restrict__ Wlin,
    float* __restrict__ XL, float* __restrict__ XR, float* __restrict__ LIN)
{
    const int lane = threadIdx.x & 63;
    const int wv   = threadIdx.x >> 6;
    const int c    = blockIdx.y * 64 + lane;   // 0..383
    const int cs   = c & 127;

    const float* Wsel;
    float* Osel;
    if (c < 128)      { Wsel = Wl;   Osel = XL;  }
    else if (c < 256) { Wsel = Wr;   Osel = XR;  }
    else              { Wsel = Wlin; Osel = LIN; }

    const int r0 = (blockIdx.x * 4 + wv) * 8;
    if (r0 >= N_NODES) return;
    const int nr = min(8, N_NODES - r0);

    float acc[8] = {0.f,0.f,0.f,0.f,0.f,0.f,0.f,0.f};

    if (nr == 8) {
        for (int k4 = 0; k4 < 32; ++k4) {
            const float w0 = Wsel[(4*k4+0)*128 + cs];
            const float w1 = Wsel[(4*k4+1)*128 + cs];
            const float w2 = Wsel[(4*k4+2)*128 + cs];
            const float w3 = Wsel[(4*k4+3)*128 + cs];
            #pragma unroll
            for (int rr = 0; rr < 8; ++rr) {
                const float4 a = ((const float4*)(x + (size_t)(r0+rr)*128))[k4];
                acc[rr] = fmaf(a.x, w0, fmaf(a.y, w1, fmaf(a.z, w2, fmaf(a.w, w3, acc[rr]))));
            }
        }
        #pragma unroll
        for (int rr = 0; rr < 8; ++rr)
            Osel[(size_t)(r0+rr)*128 + cs] = acc[rr];
    } else {
        for (int k = 0; k < 128; ++k) {
            const float w = Wsel[k*128 + cs];
            for (int rr = 0; rr < nr; ++rr)
                acc[rr] = fmaf(x[(size_t)(r0+rr)*128 + k], w, acc[rr]);
        }
        for (int rr = 0; rr < nr; ++rr)
            Osel[(size_t)(r0+rr)*128 + cs] = acc[rr];
    }
}

// ---------------------------------------------------------------------------
// Kernel 2: layer-1 edge scores. One 64-lane wave per edge.
// e = att . leaky_relu(xl[src] + xr[dst]);  expe[e] = exp(e); denom[dst] += expe
// (segment-max skipped: softmax is shift-invariant, |e| is O(1) in f32)
// ---------------------------------------------------------------------------
__global__ __launch_bounds__(256) void score1_kernel(
    const float* __restrict__ xl, const float* __restrict__ xr,
    const int* __restrict__ eidx, const float* __restrict__ att,
    float* __restrict__ expe, float* __restrict__ denom)
{
    const int gid  = blockIdx.x * blockDim.x + threadIdx.x;
    const int widx = gid >> 6;
    const int lane = gid & 63;
    if (widx >= E_TOT) return;

    int s, d;
    if (widx < E_RAW) { s = eidx[widx]; d = eidx[E_RAW + widx]; }
    else              { s = d = widx - E_RAW; }

    const float2 a  = ((const float2*)(xl + (size_t)s*128))[lane];
    const float2 b  = ((const float2*)(xr + (size_t)d*128))[lane];
    const float2 at = ((const float2*)att)[lane];

    float m0 = a.x + b.x, m1 = a.y + b.y;
    m0 = m0 > 0.f ? m0 : NEG_SLOPE * m0;
    m1 = m1 > 0.f ? m1 : NEG_SLOPE * m1;
    float v = m0 * at.x + m1 * at.y;

    #pragma unroll
    for (int off = 32; off > 0; off >>= 1) v += __shfl_xor(v, off);

    if (lane == 0) {
        const float ex = expf(v);
        expe[widx] = ex;
        atomicAdd(&denom[d], ex);
    }
}

// ---------------------------------------------------------------------------
// Kernel 3: layer-1 aggregation. One wave per edge:
// acc[dst] += (expe[e]/denom[dst]) * xl[src]     (128 floats via atomics)
// ---------------------------------------------------------------------------
__global__ __launch_bounds__(256) void agg1_kernel(
    const float* __restrict__ xl, const int* __restrict__ eidx,
    const float* __restrict__ expe, const float* __restrict__ denom,
    float* __restrict__ acc)
{
    const int gid  = blockIdx.x * blockDim.x + threadIdx.x;
    const int widx = gid >> 6;
    const int lane = gid & 63;
    if (widx >= E_TOT) return;

    int s, d;
    if (widx < E_RAW) { s = eidx[widx]; d = eidx[E_RAW + widx]; }
    else              { s = d = widx - E_RAW; }

    const float w = expe[widx] / denom[d];
    const float2 a = ((const float2*)(xl + (size_t)s*128))[lane];
    float* dst = acc + (size_t)d*128 + 2*lane;
    atomicAdd(dst,     w * a.x);
    atomicAdd(dst + 1, w * a.y);
}

// ---------------------------------------------------------------------------
// Kernel 4: H = relu(ACC + b1 + LIN + blin1)   elementwise [N,128] -> H
// ---------------------------------------------------------------------------
__global__ __launch_bounds__(256) void hidden_kernel(
    const float* __restrict__ acc, const float* __restrict__ lin,
    const float* __restrict__ b1, const float* __restrict__ blin1,
    float* __restrict__ h)
{
    const size_t idx = (size_t)blockIdx.x * blockDim.x + threadIdx.x;
    if (idx >= (size_t)N_NODES * 128) return;
    const int j = (int)(idx & 127);
    const float v = acc[idx] + b1[j] + lin[idx] + blin1[j];
    h[idx] = v > 0.f ? v : 0.f;
}

// ---------------------------------------------------------------------------
// Kernel 5: layer-2 small GEMM.  One wave per row:
// XL2 = h@Wl2, XR2 = h@Wr2, LIN2 = h@Wlin2   (each [N,2])
// ---------------------------------------------------------------------------
__global__ __launch_bounds__(256) void gemm2_kernel(
    const float* __restrict__ h,
    const float* __restrict__ Wl2, const float* __restrict__ Wr2,
    const float* __restrict__ Wlin2,
    float* __restrict__ XL2, float* __restrict__ XR2, float* __restrict__ LIN2)
{
    const int gid  = blockIdx.x * blockDim.x + threadIdx.x;
    const int row  = gid >> 6;
    const int lane = gid & 63;
    if (row >= N_NODES) return;

    const float2 hv = ((const float2*)(h + (size_t)row*128))[lane];
    const int k0 = 2*lane, k1 = 2*lane + 1;

    float v[6];
    v[0] = hv.x * Wl2[k0*2+0]   + hv.y * Wl2[k1*2+0];
    v[1] = hv.x * Wl2[k0*2+1]   + hv.y * Wl2[k1*2+1];
    v[2] = hv.x * Wr2[k0*2+0]   + hv.y * Wr2[k1*2+0];
    v[3] = hv.x * Wr2[k0*2+1]   + hv.y * Wr2[k1*2+1];
    v[4] = hv.x * Wlin2[k0*2+0] + hv.y * Wlin2[k1*2+0];
    v[5] = hv.x * Wlin2[k0*2+1] + hv.y * Wlin2[k1*2+1];

    #pragma unroll
    for (int off = 32; off > 0; off >>= 1) {
        #pragma unroll
        for (int j = 0; j < 6; ++j) v[j] += __shfl_xor(v[j], off);
    }

    if (lane == 0) {
        XL2[row*2+0]  = v[0]; XL2[row*2+1]  = v[1];
        XR2[row*2+0]  = v[2]; XR2[row*2+1]  = v[3];
        LIN2[row*2+0] = v[4]; LIN2[row*2+1] = v[5];
    }
}

// ---------------------------------------------------------------------------
// Kernel 6: layer-2 edge scores (C=2). One thread per edge.
// ---------------------------------------------------------------------------
__global__ __launch_bounds__(256) void score2_kernel(
    const float* __restrict__ XL2, const float* __restrict__ XR2,
    const int* __restrict__ eidx, const float* __restrict__ att2,
    float* __restrict__ expe, float* __restrict__ denom)
{
    const int e = blockIdx.x * blockDim.x + threadIdx.x;
    if (e >= E_TOT) return;
    int s, d;
    if (e < E_RAW) { s = eidx[e]; d = eidx[E_RAW + e]; }
    else           { s = d = e - E_RAW; }

    float m0 = XL2[s*2+0] + XR2[d*2+0];
    float m1 = XL2[s*2+1] + XR2[d*2+1];
    m0 = m0 > 0.f ? m0 : NEG_SLOPE * m0;
    m1 = m1 > 0.f ? m1 : NEG_SLOPE * m1;
    const float v  = m0 * att2[0] + m1 * att2[1];
    const float ex = expf(v);
    expe[e] = ex;
    atomicAdd(&denom[d], ex);
}

// ---------------------------------------------------------------------------
// Kernel 7: layer-2 aggregation. One thread per edge.
// ---------------------------------------------------------------------------
__global__ __launch_bounds__(256) void agg2_kernel(
    const float* __restrict__ XL2, const int* __restrict__ eidx,
    const float* __restrict__ expe, const float* __restrict__ denom,
    float* __restrict__ acc2)
{
    const int e = blockIdx.x * blockDim.x + threadIdx.x;
    if (e >= E_TOT) return;
    int s, d;
    if (e < E_RAW) { s = eidx[e]; d = eidx[E_RAW + e]; }
    else           { s = d = e - E_RAW; }

    const float w = expe[e] / denom[d];
    atomicAdd(&acc2[d*2+0], w * XL2[s*2+0]);
    atomicAdd(&acc2[d*2+1], w * XL2[s*2+1]);
}

// ---------------------------------------------------------------------------
// Kernel 8: final out = log_softmax(ACC2 + b2 + LIN2 + blin2)  -> d_out[0:100000]
// ---------------------------------------------------------------------------
__global__ __launch_bounds__(256) void final_kernel(
    const float* __restrict__ acc2, const float* __restrict__ lin2,
    const float* __restrict__ b2, const float* __restrict__ blin2,
    float* __restrict__ out)
{
    const int i = blockIdx.x * blockDim.x + threadIdx.x;
    if (i >= N_NODES) return;
    const float o0 = acc2[i*2+0] + b2[0] + lin2[i*2+0] + blin2[0];
    const float o1 = acc2[i*2+1] + b2[1] + lin2[i*2+1] + blin2[1];
    const float mx  = fmaxf(o0, o1);
    const float lse = mx + logf(expf(o0 - mx) + expf(o1 - mx));
    out[i*2+0] = o0 - lse;
    out[i*2+1] = o1 - lse;
}

// ---------------------------------------------------------------------------
// Kernel 9: copy edge_index (int32) -> d_out[100000:] as float32
// ---------------------------------------------------------------------------
__global__ __launch_bounds__(256) void copy_eidx_kernel(
    const int* __restrict__ eidx, float* __restrict__ out)
{
    const int i = blockIdx.x * blockDim.x + threadIdx.x;
    if (i >= 2 * E_RAW) return;
    out[i] = (float)eidx[i];
}

// ---------------------------------------------------------------------------
extern "C" void kernel_launch(void* const* d_in, const int* in_sizes, int n_in,
                              void* d_out, int out_size, void* d_ws, size_t ws_size,
                              hipStream_t stream)
{
    const float* x      = (const float*)d_in[0];
    const int*   eidx   = (const int*)  d_in[1];
    const float* Wl1    = (const float*)d_in[2];
    const float* Wr1    = (const float*)d_in[3];
    const float* att1   = (const float*)d_in[4];
    const float* b1     = (const float*)d_in[5];
    const float* Wlin1  = (const float*)d_in[6];
    const float* blin1  = (const float*)d_in[7];
    const float* Wl2    = (const float*)d_in[8];
    const float* Wr2    = (const float*)d_in[9];
    const float* att2   = (const float*)d_in[10];
    const float* b2     = (const float*)d_in[11];
    const float* Wlin2  = (const float*)d_in[12];
    const float* blin2  = (const float*)d_in[13];

    float* out = (float*)d_out;

    // workspace layout (floats)
    float* ws    = (float*)d_ws;
    float* XL    = ws;                       // [N,128]  6.4M
    float* XR    = ws + 6400000;             // [N,128]  6.4M  (reused as ACC)
    float* LIN   = ws + 12800000;            // [N,128]  6.4M  (reused for layer-2 vecs)
    float* EXPE  = ws + 19200000;            // [E_TOT]  850K
    float* DENOM = ws + 20050000;            // [N]      50K
    float* ACC   = XR;                       // aliases
    float* XL2   = LIN;                      // [N,2]
    float* XR2   = LIN + 100000;             // [N,2]
    float* LIN2  = LIN + 200000;             // [N,2]
    float* ACC2  = LIN + 300000;             // [N,2]

    // --- Layer 1 ---
    {
        dim3 grid((N_NODES + 31) / 32, 6);
        gemm1_kernel<<<grid, 256, 0, stream>>>(x, Wl1, Wr1, Wlin1, XL, XR, LIN);
    }
    hipMemsetAsync(DENOM, 0, N_NODES * sizeof(float), stream);
    {
        const int blocks = (E_TOT * 64 + 255) / 256;
        score1_kernel<<<blocks, 256, 0, stream>>>(XL, XR, eidx, att1, EXPE, DENOM);
    }
    hipMemsetAsync(ACC, 0, (size_t)N_NODES * 128 * sizeof(float), stream);
    {
        const int blocks = (E_TOT * 64 + 255) / 256;
        agg1_kernel<<<blocks, 256, 0, stream>>>(XL, eidx, EXPE, DENOM, ACC);
    }
    {
        const int blocks = (N_NODES * 128 + 255) / 256;
        // H written into XL (XL dead after agg1)
        hidden_kernel<<<blocks, 256, 0, stream>>>(ACC, LIN, b1, blin1, XL);
    }

    // --- Layer 2 ---
    {
        const int blocks = (N_NODES * 64 + 255) / 256;
        gemm2_kernel<<<blocks, 256, 0, stream>>>(XL, Wl2, Wr2, Wlin2, XL2, XR2, LIN2);
    }
    hipMemsetAsync(DENOM, 0, N_NODES * sizeof(float), stream);
    {
        const int blocks = (E_TOT + 255) / 256;
        score2_kernel<<<blocks, 256, 0, stream>>>(XL2, XR2, eidx, att2, EXPE, DENOM);
    }
    hipMemsetAsync(ACC2, 0, (size_t)N_NODES * 2 * sizeof(float), stream);
    {
        const int blocks = (E_TOT + 255) / 256;
        agg2_kernel<<<blocks, 256, 0, stream>>>(XL2, eidx, EXPE, DENOM, ACC2);
    }
    {
        const int blocks = (N_NODES + 255) / 256;
        final_kernel<<<blocks, 256, 0, stream>>>(ACC2, LIN2, b2, blin2, out);
    }
    {
        const int blocks = (2 * E_RAW + 255) / 256;
        copy_eidx_kernel<<<blocks, 256, 0, stream>>>(eidx, out + (size_t)N_NODES * N_CLS);
    }
}

// Round 2
// 693.011 us; speedup vs baseline: 2.0961x; 2.0961x over previous
//
#include <hip/hip_runtime.h>
#include <math.h>

#define N_NODES 50000
#define F_IN 128
#define E_RAW 800000
#define E_TOT (E_RAW + N_NODES)   // self-loops appended
#define NEG_SLOPE 0.2f

// ---------------------------------------------------------------------------
// Kernel 1: fused GEMM  X[N,128] @ [Wl1 | Wr1 | Wlin1] -> XL, XR, LIN
// ---------------------------------------------------------------------------
__global__ __launch_bounds__(256) void gemm1_kernel(
    const float* __restrict__ x,
    const float* __restrict__ Wl, const float* __restrict__ Wr,
    const float* __restrict__ Wlin,
    float* __restrict__ XL, float* __restrict__ XR, float* __restrict__ LIN)
{
    const int lane = threadIdx.x & 63;
    const int wv   = threadIdx.x >> 6;
    const int c    = blockIdx.y * 64 + lane;   // 0..383
    const int cs   = c & 127;

    const float* Wsel;
    float* Osel;
    if (c < 128)      { Wsel = Wl;   Osel = XL;  }
    else if (c < 256) { Wsel = Wr;   Osel = XR;  }
    else              { Wsel = Wlin; Osel = LIN; }

    const int r0 = (blockIdx.x * 4 + wv) * 8;
    if (r0 >= N_NODES) return;
    const int nr = min(8, N_NODES - r0);

    float acc[8] = {0.f,0.f,0.f,0.f,0.f,0.f,0.f,0.f};

    if (nr == 8) {
        for (int k4 = 0; k4 < 32; ++k4) {
            const float w0 = Wsel[(4*k4+0)*128 + cs];
            const float w1 = Wsel[(4*k4+1)*128 + cs];
            const float w2 = Wsel[(4*k4+2)*128 + cs];
            const float w3 = Wsel[(4*k4+3)*128 + cs];
            #pragma unroll
            for (int rr = 0; rr < 8; ++rr) {
                const float4 a = ((const float4*)(x + (size_t)(r0+rr)*128))[k4];
                acc[rr] = fmaf(a.x, w0, fmaf(a.y, w1, fmaf(a.z, w2, fmaf(a.w, w3, acc[rr]))));
            }
        }
        #pragma unroll
        for (int rr = 0; rr < 8; ++rr)
            Osel[(size_t)(r0+rr)*128 + cs] = acc[rr];
    } else {
        for (int k = 0; k < 128; ++k) {
            const float w = Wsel[k*128 + cs];
            for (int rr = 0; rr < nr; ++rr)
                acc[rr] = fmaf(x[(size_t)(r0+rr)*128 + k], w, acc[rr]);
        }
        for (int rr = 0; rr < nr; ++rr)
            Osel[(size_t)(r0+rr)*128 + cs] = acc[rr];
    }
}

// ---------------------------------------------------------------------------
// CSR build: histogram of dst, exclusive scan, scatter src ids
// ---------------------------------------------------------------------------
__global__ __launch_bounds__(256) void hist_kernel(
    const int* __restrict__ eidx, int* __restrict__ counts)
{
    const int e = blockIdx.x * blockDim.x + threadIdx.x;
    if (e >= E_TOT) return;
    const int d = (e < E_RAW) ? eidx[E_RAW + e] : e - E_RAW;
    atomicAdd(&counts[d], 1);
}

// single-block scan: counts[50000] -> exclusive rowptr[50001], cursor copy
// (cursor may alias counts: each thread reads counts[i] before writing cursor[i])
__global__ __launch_bounds__(1024) void scan_kernel(
    const int* __restrict__ counts, int* __restrict__ rowptr, int* __restrict__ cursor)
{
    __shared__ int wsum[16];
    __shared__ int carry_s;
    const int tid = threadIdx.x, lane = tid & 63, wv = tid >> 6;
    if (tid == 0) carry_s = 0;
    __syncthreads();

    for (int base = 0; base < N_NODES; base += 1024) {
        const int i = base + tid;
        const int orig = (i < N_NODES) ? counts[i] : 0;
        int v = orig;
        #pragma unroll
        for (int off = 1; off < 64; off <<= 1) {
            int t = __shfl_up(v, off);
            if (lane >= off) v += t;
        }
        if (lane == 63) wsum[wv] = v;
        __syncthreads();
        if (wv == 0) {
            int s = (lane < 16) ? wsum[lane] : 0;
            #pragma unroll
            for (int off = 1; off < 16; off <<= 1) {
                int t = __shfl_up(s, off);
                if (lane >= off) s += t;
            }
            if (lane < 16) wsum[lane] = s;   // inclusive wave-sum scan
        }
        __syncthreads();
        const int carry = carry_s;
        const int woff  = (wv == 0) ? 0 : wsum[wv - 1];
        const int excl  = carry + woff + v - orig;
        if (i < N_NODES) { rowptr[i] = excl; cursor[i] = excl; }
        __syncthreads();
        if (tid == 0) carry_s += wsum[15];
        __syncthreads();
    }
    if (threadIdx.x == 0) rowptr[N_NODES] = carry_s;
}

__global__ __launch_bounds__(256) void scatter_kernel(
    const int* __restrict__ eidx, int* __restrict__ cursor, int* __restrict__ csr_src)
{
    const int e = blockIdx.x * blockDim.x + threadIdx.x;
    if (e >= E_TOT) return;
    int s, d;
    if (e < E_RAW) { s = eidx[e]; d = eidx[E_RAW + e]; }
    else           { s = d = e - E_RAW; }
    const int pos = atomicAdd(&cursor[d], 1);
    csr_src[pos] = s;
}

// ---------------------------------------------------------------------------
// Fused layer-1 GAT: one wave per dst node. score+softmax+aggregate+bias+skip+relu
// Softmax shift skipped (shift-invariant; |e| is O(10), safe in f32).
// h may alias xr: xr[d] read before h[d] written, and only xl is gathered.
// ---------------------------------------------------------------------------
__global__ __launch_bounds__(256) void fused1_kernel(
    const float* __restrict__ xl, const float* __restrict__ xr,
    const float* __restrict__ lin,
    const int* __restrict__ rowptr, const int* __restrict__ csr_src,
    const float* __restrict__ att, const float* __restrict__ b1,
    const float* __restrict__ blin1,
    float* __restrict__ h)
{
    const int gid  = blockIdx.x * blockDim.x + threadIdx.x;
    const int d    = gid >> 6;
    const int lane = gid & 63;
    if (d >= N_NODES) return;

    const int r0 = rowptr[d], r1 = rowptr[d + 1];
    const float2 xrd = ((const float2*)(xr + (size_t)d * 128))[lane];
    const float2 at  = ((const float2*)att)[lane];

    float num0 = 0.f, num1 = 0.f, den = 0.f;
    for (int j = r0; j < r1; ++j) {
        const int s = csr_src[j];
        const float2 a = ((const float2*)(xl + (size_t)s * 128))[lane];
        float m0 = a.x + xrd.x, m1 = a.y + xrd.y;
        m0 = m0 > 0.f ? m0 : NEG_SLOPE * m0;
        m1 = m1 > 0.f ? m1 : NEG_SLOPE * m1;
        float v = m0 * at.x + m1 * at.y;
        #pragma unroll
        for (int off = 32; off > 0; off >>= 1) v += __shfl_xor(v, off);
        const float ex = __expf(v);
        den += ex;
        num0 = fmaf(ex, a.x, num0);
        num1 = fmaf(ex, a.y, num1);
    }
    const float inv = 1.f / den;   // den >= exp(self-loop) > 0
    const float2 lv = ((const float2*)(lin   + (size_t)d * 128))[lane];
    const float2 bb = ((const float2*)b1)[lane];
    const float2 bl = ((const float2*)blin1)[lane];
    float h0 = fmaf(num0, inv, bb.x) + lv.x + bl.x;
    float h1 = fmaf(num1, inv, bb.y) + lv.y + bl.y;
    h0 = h0 > 0.f ? h0 : 0.f;
    h1 = h1 > 0.f ? h1 : 0.f;
    ((float2*)(h + (size_t)d * 128))[lane] = make_float2(h0, h1);
}

// ---------------------------------------------------------------------------
// Layer-2 small GEMM: one wave per row -> XL2, XR2, LIN2 (each [N,2])
// ---------------------------------------------------------------------------
__global__ __launch_bounds__(256) void gemm2_kernel(
    const float* __restrict__ h,
    const float* __restrict__ Wl2, const float* __restrict__ Wr2,
    const float* __restrict__ Wlin2,
    float* __restrict__ XL2, float* __restrict__ XR2, float* __restrict__ LIN2)
{
    const int gid  = blockIdx.x * blockDim.x + threadIdx.x;
    const int row  = gid >> 6;
    const int lane = gid & 63;
    if (row >= N_NODES) return;

    const float2 hv = ((const float2*)(h + (size_t)row * 128))[lane];
    const int k0 = 2 * lane, k1 = 2 * lane + 1;

    float v[6];
    v[0] = hv.x * Wl2[k0*2+0]   + hv.y * Wl2[k1*2+0];
    v[1] = hv.x * Wl2[k0*2+1]   + hv.y * Wl2[k1*2+1];
    v[2] = hv.x * Wr2[k0*2+0]   + hv.y * Wr2[k1*2+0];
    v[3] = hv.x * Wr2[k0*2+1]   + hv.y * Wr2[k1*2+1];
    v[4] = hv.x * Wlin2[k0*2+0] + hv.y * Wlin2[k1*2+0];
    v[5] = hv.x * Wlin2[k0*2+1] + hv.y * Wlin2[k1*2+1];

    #pragma unroll
    for (int off = 32; off > 0; off >>= 1) {
        #pragma unroll
        for (int j = 0; j < 6; ++j) v[j] += __shfl_xor(v[j], off);
    }

    if (lane == 0) {
        XL2[row*2+0]  = v[0]; XL2[row*2+1]  = v[1];
        XR2[row*2+0]  = v[2]; XR2[row*2+1]  = v[3];
        LIN2[row*2+0] = v[4]; LIN2[row*2+1] = v[5];
    }
}

// ---------------------------------------------------------------------------
// Fused layer-2 GAT + bias + skip + log_softmax: one thread per node.
// ---------------------------------------------------------------------------
__global__ __launch_bounds__(256) void fused2_kernel(
    const float* __restrict__ XL2, const float* __restrict__ XR2,
    const float* __restrict__ LIN2,
    const int* __restrict__ rowptr, const int* __restrict__ csr_src,
    const float* __restrict__ att2, const float* __restrict__ b2,
    const float* __restrict__ blin2,
    float* __restrict__ out)
{
    const int d = blockIdx.x * blockDim.x + threadIdx.x;
    if (d >= N_NODES) return;

    const int r0 = rowptr[d], r1 = rowptr[d + 1];
    const float xr0 = XR2[d*2+0], xr1 = XR2[d*2+1];
    const float a0 = att2[0], a1 = att2[1];

    float num0 = 0.f, num1 = 0.f, den = 0.f;
    for (int j = r0; j < r1; ++j) {
        const int s = csr_src[j];
        const float l0 = XL2[s*2+0], l1 = XL2[s*2+1];
        float m0 = l0 + xr0, m1 = l1 + xr1;
        m0 = m0 > 0.f ? m0 : NEG_SLOPE * m0;
        m1 = m1 > 0.f ? m1 : NEG_SLOPE * m1;
        const float ex = __expf(m0 * a0 + m1 * a1);
        den += ex;
        num0 = fmaf(ex, l0, num0);
        num1 = fmaf(ex, l1, num1);
    }
    const float inv = 1.f / den;
    const float o0 = num0 * inv + b2[0] + LIN2[d*2+0] + blin2[0];
    const float o1 = num1 * inv + b2[1] + LIN2[d*2+1] + blin2[1];
    const float mx  = fmaxf(o0, o1);
    const float lse = mx + logf(__expf(o0 - mx) + __expf(o1 - mx));
    out[d*2+0] = o0 - lse;
    out[d*2+1] = o1 - lse;
}

// ---------------------------------------------------------------------------
// copy edge_index (int32) -> d_out tail as float32
// ---------------------------------------------------------------------------
__global__ __launch_bounds__(256) void copy_eidx_kernel(
    const int* __restrict__ eidx, float* __restrict__ out)
{
    const int i = blockIdx.x * blockDim.x + threadIdx.x;
    if (i >= 2 * E_RAW) return;
    out[i] = (float)eidx[i];
}

// ---------------------------------------------------------------------------
extern "C" void kernel_launch(void* const* d_in, const int* in_sizes, int n_in,
                              void* d_out, int out_size, void* d_ws, size_t ws_size,
                              hipStream_t stream)
{
    const float* x      = (const float*)d_in[0];
    const int*   eidx   = (const int*)  d_in[1];
    const float* Wl1    = (const float*)d_in[2];
    const float* Wr1    = (const float*)d_in[3];
    const float* att1   = (const float*)d_in[4];
    const float* b1     = (const float*)d_in[5];
    const float* Wlin1  = (const float*)d_in[6];
    const float* blin1  = (const float*)d_in[7];
    const float* Wl2    = (const float*)d_in[8];
    const float* Wr2    = (const float*)d_in[9];
    const float* att2   = (const float*)d_in[10];
    const float* b2     = (const float*)d_in[11];
    const float* Wlin2  = (const float*)d_in[12];
    const float* blin2  = (const float*)d_in[13];

    float* out = (float*)d_out;

    // workspace layout (4-byte elements)
    float* ws     = (float*)d_ws;
    float* XL     = ws;                        // [N,128]
    float* XR     = ws + 6400000;              // [N,128]  (fused1 writes H in-place)
    float* LIN    = ws + 12800000;             // [N,128]  (reused for layer-2 vecs)
    int*   counts = (int*)(ws + 19200000);     // [N]  (also scatter cursor)
    int*   rowptr = counts + 50000;            // [N+1]
    int*   csr    = rowptr + 50001;            // [E_TOT]
    float* H      = XR;
    float* XL2    = LIN;                       // [N,2] — LIN data dead after fused1
    float* XR2    = LIN + 100000;
    float* LIN2   = LIN + 200000;

    // --- Layer-1 GEMM ---
    {
        dim3 grid((N_NODES + 31) / 32, 6);
        gemm1_kernel<<<grid, 256, 0, stream>>>(x, Wl1, Wr1, Wlin1, XL, XR, LIN);
    }

    // --- CSR build (independent of GEMM, same stream) ---
    hipMemsetAsync(counts, 0, N_NODES * sizeof(int), stream);
    hist_kernel<<<(E_TOT + 255) / 256, 256, 0, stream>>>(eidx, counts);
    scan_kernel<<<1, 1024, 0, stream>>>(counts, rowptr, counts);
    scatter_kernel<<<(E_TOT + 255) / 256, 256, 0, stream>>>(eidx, counts, csr);

    // --- Fused layer-1 GAT (wave per node) ---
    {
        const int blocks = (N_NODES * 64 + 255) / 256;
        fused1_kernel<<<blocks, 256, 0, stream>>>(XL, XR, LIN, rowptr, csr,
                                                  att1, b1, blin1, H);
    }

    // --- Layer 2 ---
    {
        const int blocks = (N_NODES * 64 + 255) / 256;
        gemm2_kernel<<<blocks, 256, 0, stream>>>(H, Wl2, Wr2, Wlin2, XL2, XR2, LIN2);
    }
    {
        const int blocks = (N_NODES + 255) / 256;
        fused2_kernel<<<blocks, 256, 0, stream>>>(XL2, XR2, LIN2, rowptr, csr,
                                                  att2, b2, blin2, out);
    }
    {
        const int blocks = (2 * E_RAW + 255) / 256;
        copy_eidx_kernel<<<blocks, 256, 0, stream>>>(eidx, out + (size_t)N_NODES * 2);
    }
}